// Round 9
// baseline (202.047 us; speedup 1.0000x reference)
//
#include <hip/hip_runtime.h>
#include <math.h>

#define NN 50000
#define NE 800000
#define F 64
#define NCLS 16

#define BKS 7              // log2(nodes per bucket)
#define BKN 128            // nodes per bucket
#define NBK 391            // ceil(50000/128)
#define CAP 2560           // slots per bucket region (avg 2048, sigma~45)
#define B1C 4096           // edges per bucket1 block
#define B1B 196            // ceil(NE/B1C)
#define MMB 1563           // ceil(50000/32) mm-role blocks
#define CAP2 3072          // bucket2 LDS capacity

typedef unsigned short u16;
typedef __attribute__((ext_vector_type(8))) unsigned short ushort8v;

__device__ __forceinline__ float bf2f(u16 h) {
    return __uint_as_float((unsigned)h << 16);
}
__device__ __forceinline__ u16 f2bf(float f) {   // round-nearest-even
    unsigned u = __float_as_uint(f);
    return (u16)((u + 0x7fffu + ((u >> 16) & 1u)) >> 16);
}

// cursors start at the region bases: cur[b] = b*CAP
__global__ void k_init_cur(int* __restrict__ cur) {
    int b = blockIdx.x * 256 + threadIdx.x;
    if (b < NBK) cur[b] = b * CAP;
}

// ---------------- fused: bucket1 (blocks < B1B) + layer-1 mm64 (blocks >= B1B) ----
// bucket1: group edges by dst-bucket in LDS, flush contiguous runs to slotted tmp.
// mm:      A[r,64] = x[r,64] @ W1  -> bf16, 32 rows/block (512 threads).

__global__ __launch_bounds__(512) void k_sort_mm(const int* __restrict__ row,
                                                 const int* __restrict__ col,
                                                 const float* __restrict__ w,
                                                 int* __restrict__ bkcur,
                                                 int2* __restrict__ tmp,
                                                 const float* __restrict__ X,
                                                 const float* __restrict__ W,
                                                 u16* __restrict__ Y) {
    __shared__ __align__(16) char smem[53248];   // 52 KB union
    int t = threadIdx.x;
    if (blockIdx.x < B1B) {
        // ---- bucket1 role ----
        int*  hist   = (int*)smem;               // 512
        int*  sa     = hist + 512;
        int*  sb     = sa + 512;
        int*  lbase  = sb + 512;
        int*  gbase  = lbase + 512;
        int*  lcur   = gbase + 512;
        u16*  stageB = (u16*)(lcur + 512);       // 4096 u16
        int2* stage  = (int2*)(stageB + 4096);   // 4096 int2 (offset 20480, 16B-aligned)

        int e0 = blockIdx.x * B1C;
        int cnt = min(B1C, NE - e0);
        hist[t] = 0;
        __syncthreads();

        int mykey[8]; int myb[8]; int myw[8]; bool myv[8];
#pragma unroll
        for (int k = 0; k < 8; ++k) {
            int i = t + k * 512;
            myv[k] = (i < cnt);
            if (myv[k]) {
                int e = e0 + i;
                int c = col[e];
                myb[k]   = c >> BKS;
                mykey[k] = (row[e] << BKS) | (c & (BKN - 1));
                myw[k]   = __float_as_int(w[e]);
                atomicAdd(&hist[myb[k]], 1);
            }
        }
        __syncthreads();

        sa[t] = hist[t];
        __syncthreads();
        int* src = sa; int* dst = sb;
#pragma unroll
        for (int off = 1; off < 512; off <<= 1) {
            dst[t] = src[t] + ((t >= off) ? src[t - off] : 0);
            __syncthreads();
            int* tq = src; src = dst; dst = tq;
        }
        int lex = src[t] - hist[t];
        lbase[t] = lex;
        lcur[t]  = lex;
        gbase[t] = (t < NBK && hist[t] > 0) ? atomicAdd(&bkcur[t], hist[t]) : 0;
        __syncthreads();

#pragma unroll
        for (int k = 0; k < 8; ++k) {
            if (myv[k]) {
                int pos = atomicAdd(&lcur[myb[k]], 1);
                stage[pos]  = make_int2(mykey[k], myw[k]);
                stageB[pos] = (u16)myb[k];
            }
        }
        __syncthreads();

        for (int i = t; i < cnt; i += 512) {
            int b = stageB[i];
            tmp[gbase[b] + (i - lbase[b])] = stage[i];
        }
    } else {
        // ---- mm role: 32 rows/block ----
        float* sW = (float*)smem;                        // 64*64
        float (*sX)[64] = (float(*)[64])(smem + 16384);  // 32 rows
        for (int i = t; i < 64 * 64; i += 512) sW[i] = W[i];
        int r0 = (blockIdx.x - B1B) * 32;
        for (int i = t; i < 32 * 64; i += 512) {
            int rr = i >> 6, cc = i & 63;
            int r = r0 + rr;
            sX[rr][cc] = (r < NN) ? X[(size_t)r * 64 + cc] : 0.f;
        }
        __syncthreads();
        int c  = t & 63;
        int wv = t >> 6;          // 0..7
        int rb = wv * 4;
        float a0 = 0.f, a1 = 0.f, a2 = 0.f, a3 = 0.f;
#pragma unroll
        for (int k = 0; k < 64; k += 4) {
            float4 x0 = *(const float4*)&sX[rb + 0][k];
            float4 x1 = *(const float4*)&sX[rb + 1][k];
            float4 x2 = *(const float4*)&sX[rb + 2][k];
            float4 x3 = *(const float4*)&sX[rb + 3][k];
            float wA = sW[(k + 0) * 64 + c];
            float wB = sW[(k + 1) * 64 + c];
            float wC = sW[(k + 2) * 64 + c];
            float wD = sW[(k + 3) * 64 + c];
            a0 += x0.x * wA + x0.y * wB + x0.z * wC + x0.w * wD;
            a1 += x1.x * wA + x1.y * wB + x1.z * wC + x1.w * wD;
            a2 += x2.x * wA + x2.y * wB + x2.z * wC + x2.w * wD;
            a3 += x3.x * wA + x3.y * wB + x3.z * wC + x3.w * wD;
        }
        float av[4] = {a0, a1, a2, a3};
#pragma unroll
        for (int k = 0; k < 4; ++k) {
            int r = r0 + rb + k;
            if (r < NN) Y[(size_t)r * 64 + c] = f2bf(av[k]);
        }
    }
}

// ---------------- pass 2: per-bucket node sort in LDS + beg/end + dinv ----------------

__global__ __launch_bounds__(256) void k_bucket2(const int* __restrict__ bkcur,
                                                 const int2* __restrict__ tmp,
                                                 int2* __restrict__ sedge,
                                                 int* __restrict__ begA,
                                                 int* __restrict__ endA,
                                                 float* __restrict__ dinv) {
    __shared__ int2 stage[CAP2];
    __shared__ int2 sorted[CAP2];
    __shared__ int hist[BKN];
    __shared__ int sa[BKN], sb[BKN];
    __shared__ int lcur[BKN];
    int b = blockIdx.x;
    int t = threadIdx.x;
    int rbeg = b * CAP;
    int cnt = min(bkcur[b] - rbeg, CAP2);
    if (t < BKN) hist[t] = 0;
    __syncthreads();
    for (int i = t; i < cnt; i += 256) {
        int2 ed = tmp[rbeg + i];
        stage[i] = ed;
        atomicAdd(&hist[ed.x & (BKN - 1)], 1);
    }
    __syncthreads();
    if (t < BKN) sa[t] = hist[t];
    __syncthreads();
    int* src = sa; int* dst = sb;
#pragma unroll
    for (int off = 1; off < BKN; off <<= 1) {
        if (t < BKN) dst[t] = src[t] + ((t >= off) ? src[t - off] : 0);
        __syncthreads();
        int* tq = src; src = dst; dst = tq;
    }
    int node0 = b * BKN;
    int lincl = 0, lexcl = 0;
    if (t < BKN) {
        lincl = src[t];
        lexcl = lincl - hist[t];
        lcur[t] = lexcl;
        if (node0 + t < NN) {
            begA[node0 + t] = rbeg + lexcl;
            endA[node0 + t] = rbeg + lincl;
        }
    }
    __syncthreads();
    for (int i = t; i < cnt; i += 256) {
        int2 ed = stage[i];
        int pos = atomicAdd(&lcur[ed.x & (BKN - 1)], 1);
        sorted[pos] = ed;
    }
    __syncthreads();
    if (t < BKN && node0 + t < NN) {
        float s = 1.0f;      // self-loop weight
        for (int e = lexcl; e < lincl; ++e) s += __int_as_float(sorted[e].y);
        dinv[node0 + t] = rsqrtf(s);
    }
    for (int i = t; i < cnt; i += 256) {
        int2 ed = sorted[i];
        sedge[rbeg + i] = make_int2(ed.x >> BKS, ed.y);   // {src, raw weight}
    }
}

// ---------------- dense: Y[n,64] = X[n,64] @ W[64,64], bf16 in/out (layer 2) -------

__global__ __launch_bounds__(256) void k_mm64b(const u16* __restrict__ Xv,
                                               const float* __restrict__ W,
                                               u16* __restrict__ Y) {
    __shared__ float sW[64 * 64];
    __shared__ float sX[16][64];
    int tid = threadIdx.x;
    int c  = tid & 63;
    int wv = tid >> 6;
    for (int i = tid; i < 64 * 64; i += 256) sW[i] = W[i];
    int r0 = blockIdx.x * 16;
#pragma unroll
    for (int i = tid; i < 16 * 64; i += 256) {
        size_t idx = (size_t)(r0 + (i >> 6)) * 64 + (i & 63);
        sX[i >> 6][i & 63] = bf2f(Xv[idx]);
    }
    __syncthreads();
    int rb = wv * 4;
    float a0 = 0.f, a1 = 0.f, a2 = 0.f, a3 = 0.f;
#pragma unroll
    for (int k = 0; k < 64; k += 4) {
        float4 x0 = *(const float4*)&sX[rb + 0][k];
        float4 x1 = *(const float4*)&sX[rb + 1][k];
        float4 x2 = *(const float4*)&sX[rb + 2][k];
        float4 x3 = *(const float4*)&sX[rb + 3][k];
        float wA = sW[(k + 0) * 64 + c];
        float wB = sW[(k + 1) * 64 + c];
        float wC = sW[(k + 2) * 64 + c];
        float wD = sW[(k + 3) * 64 + c];
        a0 += x0.x * wA + x0.y * wB + x0.z * wC + x0.w * wD;
        a1 += x1.x * wA + x1.y * wB + x1.z * wC + x1.w * wD;
        a2 += x2.x * wA + x2.y * wB + x2.z * wC + x2.w * wD;
        a3 += x3.x * wA + x3.y * wB + x3.z * wC + x3.w * wD;
    }
    Y[(size_t)(r0 + rb + 0) * 64 + c] = f2bf(a0);
    Y[(size_t)(r0 + rb + 1) * 64 + c] = f2bf(a1);
    Y[(size_t)(r0 + rb + 2) * 64 + c] = f2bf(a2);
    Y[(size_t)(r0 + rb + 3) * 64 + c] = f2bf(a3);
}

// ---------------- aggregation: TWO nodes per wave, unrolled MLP batch ----------------
// half = lane>>5 picks the node; within the 32-lane half: 4 edge slots x 8
// feature-lanes (ushort8). Batch 0 (edges 0..31) fully unrolled so the compiler
// issues up to 8 independent gathers per lane before the fma chains (MLP).
// deg>32 remainder uses the generic loop (rare: Poisson(16)).

template<bool HEAD>
__global__ __launch_bounds__(256) void k_agg(const u16* __restrict__ A,
                                             const int* __restrict__ begA,
                                             const int* __restrict__ endA,
                                             const int2* __restrict__ sedge,
                                             const float* __restrict__ dinv,
                                             const float* __restrict__ bias,
                                             u16* __restrict__ B,
                                             const float* __restrict__ Wout,
                                             const float* __restrict__ bout,
                                             float* __restrict__ out) {
    __shared__ float sWout[64 * NCLS];
    __shared__ float sh[8][64];
    int tid  = threadIdx.x;
    int wv   = tid >> 6;
    int lane = tid & 63;
    int half = lane >> 5;                 // node within the wave
    int sub  = lane & 31;
    int slot = sub >> 3;                  // 0..3 edge slot
    int fg   = sub & 7;                   // features fg*8 .. fg*8+7
    int node = blockIdx.x * 8 + wv * 2 + half;   // 6250*8 = 50000 exact
    if (HEAD) {
        for (int i = tid; i < 64 * NCLS; i += 256) sWout[i] = Wout[i];
    }
    int beg = begA[node];
    int deg = endA[node] - beg;
    float acc[8] = {0.f, 0.f, 0.f, 0.f, 0.f, 0.f, 0.f, 0.f};

    // ---- batch 0: edges 0..min(deg,32)-1, fully unrolled (8 steps x 4 slots) ----
    {
        int2 ed = (sub < deg) ? sedge[beg + sub] : make_int2(0, 0);   // w=0 pad
        float nmr = __int_as_float(ed.y) * dinv[ed.x];                // w * dinv[src]
        int mval = min(32, deg);          // uniform within the 32-lane half
#pragma unroll
        for (int t = 0; t < 8; ++t) {
            if ((t << 2) < mval) {
                int idx = (half << 5) + (t << 2) + slot;
                int   s  = __shfl(ed.x, idx);
                float nm = __shfl(nmr, idx);
                const ushort8v a = *(const ushort8v*)(A + (size_t)s * 64 + (fg << 3));
#pragma unroll
                for (int j = 0; j < 8; ++j) acc[j] += bf2f(a[j]) * nm;
            }
        }
    }
    // ---- remainder: deg > 32 (rare) ----
    for (int base = 32; base < deg; base += 32) {
        int i = base + sub;
        int2 ed = (i < deg) ? sedge[beg + i] : make_int2(0, 0);
        float nmr = __int_as_float(ed.y) * dinv[ed.x];
        int m = min(32, deg - base);
        int steps = (m + 3) >> 2;
        for (int t = 0; t < steps; ++t) {
            int idx = (half << 5) + (t << 2) + slot;
            int   s  = __shfl(ed.x, idx);
            float nm = __shfl(nmr, idx);
            const ushort8v a = *(const ushort8v*)(A + (size_t)s * 64 + (fg << 3));
#pragma unroll
            for (int j = 0; j < 8; ++j) acc[j] += bf2f(a[j]) * nm;
        }
    }
    // reduce across the 4 slots within each half
#pragma unroll
    for (int o = 8; o <= 16; o <<= 1) {
#pragma unroll
        for (int j = 0; j < 8; ++j) acc[j] += __shfl_xor(acc[j], o);
    }
    if (slot == 0) {                       // 8 lanes per half: fg = 0..7
        float d = dinv[node];
        float d2 = d * d;
        const ushort8v self = *(const ushort8v*)(A + (size_t)node * 64 + (fg << 3));
        const float4 bb0 = *(const float4*)(bias + (fg << 3));
        const float4 bb1 = *(const float4*)(bias + (fg << 3) + 4);
        float bbv[8] = {bb0.x, bb0.y, bb0.z, bb0.w, bb1.x, bb1.y, bb1.z, bb1.w};
        ushort8v ov;
#pragma unroll
        for (int j = 0; j < 8; ++j) {
            float v = fmaxf(acc[j] * d + bf2f(self[j]) * d2 + bbv[j], 0.f);
            ov[j] = f2bf(v);
            if (HEAD) sh[wv * 2 + half][(fg << 3) + j] = v;
        }
        *(ushort8v*)(B + (size_t)node * 64 + (fg << 3)) = ov;
    }
    if (HEAD) {
        __syncthreads();
        int nib  = tid >> 5;               // node-in-block 0..7
        int sub2 = tid & 31;
        int c = sub2 & 15, q = sub2 >> 4;
        const float* hrow = sh[nib];
        float p = 0.f;
#pragma unroll
        for (int k = 0; k < 32; ++k)
            p += hrow[q * 32 + k] * sWout[(q * 32 + k) * NCLS + c];
        p += __shfl_xor(p, 16);
        p += bout[c];
        float mx = p;
#pragma unroll
        for (int o = 8; o >= 1; o >>= 1) mx = fmaxf(mx, __shfl_xor(mx, o, 16));
        float ex = expf(p - mx);
        float s = ex;
#pragma unroll
        for (int o = 8; o >= 1; o >>= 1) s += __shfl_xor(s, o, 16);
        if (q == 0) out[(size_t)(blockIdx.x * 8 + nib) * NCLS + c] = ex / s;
    }
}

// ---------------- launch ----------------

extern "C" void kernel_launch(void* const* d_in, const int* in_sizes, int n_in,
                              void* d_out, int out_size, void* d_ws, size_t ws_size,
                              hipStream_t stream) {
    const float* x    = (const float*)d_in[0];
    const int*   ei   = (const int*)d_in[1];
    const float* ew   = (const float*)d_in[2];
    const float* W1   = (const float*)d_in[3];
    const float* b1   = (const float*)d_in[4];
    const float* W2   = (const float*)d_in[5];
    const float* b2   = (const float*)d_in[6];
    const float* Wout = (const float*)d_in[7];
    const float* bout = (const float*)d_in[8];
    const int* row = ei;
    const int* col = ei + NE;

    // workspace (tmp NOT aliased with A: mm-role writes A concurrently with bucket1)
    int*   ip     = (int*)d_ws;
    int*   begA   = ip;                               // 50048
    int*   endA   = ip + 50048;                       // 50048
    float* dinv   = (float*)(ip + 100096);            // 50048
    int*   bkcur  = ip + 150144;                      // 512
    int2*  sedge  = (int2*)(ip + 150656);             // NBK*CAP int2 (~8 MB)
    int2*  tmp    = sedge + (size_t)NBK * CAP;        // NBK*CAP int2 (~8 MB)
    u16*   A      = (u16*)(tmp + (size_t)NBK * CAP);  // NN*64 bf16 (6.4 MB)
    u16*   B      = A + 3200000;                      // NN*64 bf16 (6.4 MB)

    // sort pipeline + layer-1 matmul (overlapped)
    k_init_cur<<<2, 256, 0, stream>>>(bkcur);
    k_sort_mm<<<B1B + MMB, 512, 0, stream>>>(row, col, ew, bkcur, tmp, x, W1, A);
    k_bucket2<<<NBK, 256, 0, stream>>>(bkcur, tmp, sedge, begA, endA, dinv);

    // layer 1 aggregation
    k_agg<false><<<NN / 8, 256, 0, stream>>>(A, begA, endA, sedge, dinv, b1, B,
                                             nullptr, nullptr, nullptr);
    // layer 2 + fused head
    k_mm64b<<<NN / 16, 256, 0, stream>>>(B, W2, A);
    k_agg<true><<<NN / 8, 256, 0, stream>>>(A, begA, endA, sedge, dinv, b2, B,
                                            Wout, bout, (float*)d_out);
}

// Round 10
// 187.849 us; speedup vs baseline: 1.0756x; 1.0756x over previous
//
#include <hip/hip_runtime.h>
#include <math.h>

#define NN 50000
#define NE 800000
#define F 64
#define NCLS 16

#define BKS 7              // log2(nodes per bucket)
#define BKN 128            // nodes per bucket
#define NBK 391            // ceil(50000/128)
#define CAP 2560           // slots per bucket region (avg 2048, sigma~45)
#define B1C 4096           // edges per bucket1 block
#define B1B 196            // ceil(NE/B1C)
#define CAP2 3072          // bucket2 LDS capacity

typedef unsigned short u16;
typedef __attribute__((ext_vector_type(8))) unsigned short ushort8v;

__device__ __forceinline__ float bf2f(u16 h) {
    return __uint_as_float((unsigned)h << 16);
}
__device__ __forceinline__ u16 f2bf(float f) {   // round-nearest-even
    unsigned u = __float_as_uint(f);
    return (u16)((u + 0x7fffu + ((u >> 16) & 1u)) >> 16);
}

// cursors start at the region bases: cur[b] = b*CAP
__global__ void k_init_cur(int* __restrict__ cur) {
    int b = blockIdx.x * 256 + threadIdx.x;
    if (b < NBK) cur[b] = b * CAP;
}

// ---------------- pass 1: group edges by bucket (LDS), flush runs to slotted regions
// stageB records each staged element's bucket -> direct-index flush (no search).

__global__ __launch_bounds__(512) void k_bucket1(const int* __restrict__ row,
                                                 const int* __restrict__ col,
                                                 const float* __restrict__ w,
                                                 int* __restrict__ bkcur,
                                                 int2* __restrict__ tmp) {
    __shared__ int hist[512];
    __shared__ int sa[512], sb[512];
    __shared__ int lbase[512];
    __shared__ int gbase[512];
    __shared__ int lcur[512];
    __shared__ u16 stageB[B1C];
    __shared__ int2 stage[B1C];
    int t = threadIdx.x;
    int e0 = blockIdx.x * B1C;
    int cnt = min(B1C, NE - e0);
    hist[t] = 0;
    __syncthreads();

    int mykey[8]; int myb[8]; int myw[8]; bool myv[8];
#pragma unroll
    for (int k = 0; k < 8; ++k) {
        int i = t + k * 512;
        myv[k] = (i < cnt);
        if (myv[k]) {
            int e = e0 + i;
            int c = col[e];
            myb[k]   = c >> BKS;
            mykey[k] = (row[e] << BKS) | (c & (BKN - 1));
            myw[k]   = __float_as_int(w[e]);
            atomicAdd(&hist[myb[k]], 1);
        }
    }
    __syncthreads();

    sa[t] = hist[t];
    __syncthreads();
    int* src = sa; int* dst = sb;
#pragma unroll
    for (int off = 1; off < 512; off <<= 1) {
        dst[t] = src[t] + ((t >= off) ? src[t - off] : 0);
        __syncthreads();
        int* tq = src; src = dst; dst = tq;
    }
    int lex = src[t] - hist[t];
    lbase[t] = lex;
    lcur[t]  = lex;
    gbase[t] = (t < NBK && hist[t] > 0) ? atomicAdd(&bkcur[t], hist[t]) : 0;
    __syncthreads();

#pragma unroll
    for (int k = 0; k < 8; ++k) {
        if (myv[k]) {
            int pos = atomicAdd(&lcur[myb[k]], 1);
            stage[pos]  = make_int2(mykey[k], myw[k]);
            stageB[pos] = (u16)myb[k];
        }
    }
    __syncthreads();

    for (int i = t; i < cnt; i += 512) {
        int b = stageB[i];
        tmp[gbase[b] + (i - lbase[b])] = stage[i];
    }
}

// ---------------- pass 2: per-bucket node sort in LDS + beg/end + dinv ----------------

__global__ __launch_bounds__(256) void k_bucket2(const int* __restrict__ bkcur,
                                                 const int2* __restrict__ tmp,
                                                 int2* __restrict__ sedge,
                                                 int* __restrict__ begA,
                                                 int* __restrict__ endA,
                                                 float* __restrict__ dinv) {
    __shared__ int2 stage[CAP2];
    __shared__ int2 sorted[CAP2];
    __shared__ int hist[BKN];
    __shared__ int sa[BKN], sb[BKN];
    __shared__ int lcur[BKN];
    int b = blockIdx.x;
    int t = threadIdx.x;
    int rbeg = b * CAP;
    int cnt = min(bkcur[b] - rbeg, CAP2);
    if (t < BKN) hist[t] = 0;
    __syncthreads();
    for (int i = t; i < cnt; i += 256) {
        int2 ed = tmp[rbeg + i];
        stage[i] = ed;
        atomicAdd(&hist[ed.x & (BKN - 1)], 1);
    }
    __syncthreads();
    if (t < BKN) sa[t] = hist[t];
    __syncthreads();
    int* src = sa; int* dst = sb;
#pragma unroll
    for (int off = 1; off < BKN; off <<= 1) {
        if (t < BKN) dst[t] = src[t] + ((t >= off) ? src[t - off] : 0);
        __syncthreads();
        int* tq = src; src = dst; dst = tq;
    }
    int node0 = b * BKN;
    int lincl = 0, lexcl = 0;
    if (t < BKN) {
        lincl = src[t];
        lexcl = lincl - hist[t];
        lcur[t] = lexcl;
        if (node0 + t < NN) {
            begA[node0 + t] = rbeg + lexcl;
            endA[node0 + t] = rbeg + lincl;
        }
    }
    __syncthreads();
    for (int i = t; i < cnt; i += 256) {
        int2 ed = stage[i];
        int pos = atomicAdd(&lcur[ed.x & (BKN - 1)], 1);
        sorted[pos] = ed;
    }
    __syncthreads();
    if (t < BKN && node0 + t < NN) {
        float s = 1.0f;      // self-loop weight
        for (int e = lexcl; e < lincl; ++e) s += __int_as_float(sorted[e].y);
        dinv[node0 + t] = rsqrtf(s);
    }
    for (int i = t; i < cnt; i += 256) {
        int2 ed = sorted[i];
        sedge[rbeg + i] = make_int2(ed.x >> BKS, ed.y);   // {src, raw weight}
    }
}

// ---------------- dense: Y[n,64] = X[n,64] @ W[64,64] -> bf16 ----------------

template<bool BF>
__global__ __launch_bounds__(256) void k_mm64(const void* __restrict__ Xv,
                                              const float* __restrict__ W,
                                              u16* __restrict__ Y) {
    __shared__ float sW[64 * 64];
    __shared__ float sX[16][64];
    int tid = threadIdx.x;
    int c  = tid & 63;
    int wv = tid >> 6;
    for (int i = tid; i < 64 * 64; i += 256) sW[i] = W[i];
    int r0 = blockIdx.x * 16;
#pragma unroll
    for (int i = tid; i < 16 * 64; i += 256) {
        size_t idx = (size_t)(r0 + (i >> 6)) * 64 + (i & 63);
        if (BF) sX[i >> 6][i & 63] = bf2f(((const u16*)Xv)[idx]);
        else    sX[i >> 6][i & 63] = ((const float*)Xv)[idx];
    }
    __syncthreads();
    int rb = wv * 4;
    float a0 = 0.f, a1 = 0.f, a2 = 0.f, a3 = 0.f;
#pragma unroll
    for (int k = 0; k < 64; k += 4) {
        float4 x0 = *(const float4*)&sX[rb + 0][k];
        float4 x1 = *(const float4*)&sX[rb + 1][k];
        float4 x2 = *(const float4*)&sX[rb + 2][k];
        float4 x3 = *(const float4*)&sX[rb + 3][k];
        float wA = sW[(k + 0) * 64 + c];
        float wB = sW[(k + 1) * 64 + c];
        float wC = sW[(k + 2) * 64 + c];
        float wD = sW[(k + 3) * 64 + c];
        a0 += x0.x * wA + x0.y * wB + x0.z * wC + x0.w * wD;
        a1 += x1.x * wA + x1.y * wB + x1.z * wC + x1.w * wD;
        a2 += x2.x * wA + x2.y * wB + x2.z * wC + x2.w * wD;
        a3 += x3.x * wA + x3.y * wB + x3.z * wC + x3.w * wD;
    }
    Y[(size_t)(r0 + rb + 0) * 64 + c] = f2bf(a0);
    Y[(size_t)(r0 + rb + 1) * 64 + c] = f2bf(a1);
    Y[(size_t)(r0 + rb + 2) * 64 + c] = f2bf(a2);
    Y[(size_t)(r0 + rb + 3) * 64 + c] = f2bf(a3);
}

// ---------------- aggregation: TWO nodes per wave, unrolled MLP batch ----------------
// half = lane>>5 picks the node; within the 32-lane half: 4 edge slots x 8
// feature-lanes (ushort8). Batch 0 (edges 0..31) fully unrolled so the compiler
// issues up to 8 independent gathers per lane before the fma chains (MLP).
// deg>32 remainder uses the generic loop (rare: Poisson(16)).

template<bool HEAD>
__global__ __launch_bounds__(256) void k_agg(const u16* __restrict__ A,
                                             const int* __restrict__ begA,
                                             const int* __restrict__ endA,
                                             const int2* __restrict__ sedge,
                                             const float* __restrict__ dinv,
                                             const float* __restrict__ bias,
                                             u16* __restrict__ B,
                                             const float* __restrict__ Wout,
                                             const float* __restrict__ bout,
                                             float* __restrict__ out) {
    __shared__ float sWout[64 * NCLS];
    __shared__ float sh[8][64];
    int tid  = threadIdx.x;
    int wv   = tid >> 6;
    int lane = tid & 63;
    int half = lane >> 5;                 // node within the wave
    int sub  = lane & 31;
    int slot = sub >> 3;                  // 0..3 edge slot
    int fg   = sub & 7;                   // features fg*8 .. fg*8+7
    int node = blockIdx.x * 8 + wv * 2 + half;   // 6250*8 = 50000 exact
    if (HEAD) {
        for (int i = tid; i < 64 * NCLS; i += 256) sWout[i] = Wout[i];
    }
    int beg = begA[node];
    int deg = endA[node] - beg;
    float acc[8] = {0.f, 0.f, 0.f, 0.f, 0.f, 0.f, 0.f, 0.f};

    // ---- batch 0: edges 0..min(deg,32)-1, fully unrolled (8 steps x 4 slots) ----
    {
        int2 ed = (sub < deg) ? sedge[beg + sub] : make_int2(0, 0);   // w=0 pad
        float nmr = __int_as_float(ed.y) * dinv[ed.x];                // w * dinv[src]
        int mval = min(32, deg);          // uniform within the 32-lane half
#pragma unroll
        for (int t = 0; t < 8; ++t) {
            if ((t << 2) < mval) {
                int idx = (half << 5) + (t << 2) + slot;
                int   s  = __shfl(ed.x, idx);
                float nm = __shfl(nmr, idx);
                const ushort8v a = *(const ushort8v*)(A + (size_t)s * 64 + (fg << 3));
#pragma unroll
                for (int j = 0; j < 8; ++j) acc[j] += bf2f(a[j]) * nm;
            }
        }
    }
    // ---- remainder: deg > 32 (rare) ----
    for (int base = 32; base < deg; base += 32) {
        int i = base + sub;
        int2 ed = (i < deg) ? sedge[beg + i] : make_int2(0, 0);
        float nmr = __int_as_float(ed.y) * dinv[ed.x];
        int m = min(32, deg - base);
        int steps = (m + 3) >> 2;
        for (int t = 0; t < steps; ++t) {
            int idx = (half << 5) + (t << 2) + slot;
            int   s  = __shfl(ed.x, idx);
            float nm = __shfl(nmr, idx);
            const ushort8v a = *(const ushort8v*)(A + (size_t)s * 64 + (fg << 3));
#pragma unroll
            for (int j = 0; j < 8; ++j) acc[j] += bf2f(a[j]) * nm;
        }
    }
    // reduce across the 4 slots within each half
#pragma unroll
    for (int o = 8; o <= 16; o <<= 1) {
#pragma unroll
        for (int j = 0; j < 8; ++j) acc[j] += __shfl_xor(acc[j], o);
    }
    if (slot == 0) {                       // 8 lanes per half: fg = 0..7
        float d = dinv[node];
        float d2 = d * d;
        const ushort8v self = *(const ushort8v*)(A + (size_t)node * 64 + (fg << 3));
        const float4 bb0 = *(const float4*)(bias + (fg << 3));
        const float4 bb1 = *(const float4*)(bias + (fg << 3) + 4);
        float bbv[8] = {bb0.x, bb0.y, bb0.z, bb0.w, bb1.x, bb1.y, bb1.z, bb1.w};
        ushort8v ov;
#pragma unroll
        for (int j = 0; j < 8; ++j) {
            float v = fmaxf(acc[j] * d + bf2f(self[j]) * d2 + bbv[j], 0.f);
            ov[j] = f2bf(v);
            if (HEAD) sh[wv * 2 + half][(fg << 3) + j] = v;
        }
        *(ushort8v*)(B + (size_t)node * 64 + (fg << 3)) = ov;
    }
    if (HEAD) {
        __syncthreads();
        int nib  = tid >> 5;               // node-in-block 0..7
        int sub2 = tid & 31;
        int c = sub2 & 15, q = sub2 >> 4;
        const float* hrow = sh[nib];
        float p = 0.f;
#pragma unroll
        for (int k = 0; k < 32; ++k)
            p += hrow[q * 32 + k] * sWout[(q * 32 + k) * NCLS + c];
        p += __shfl_xor(p, 16);
        p += bout[c];
        float mx = p;
#pragma unroll
        for (int o = 8; o >= 1; o >>= 1) mx = fmaxf(mx, __shfl_xor(mx, o, 16));
        float ex = expf(p - mx);
        float s = ex;
#pragma unroll
        for (int o = 8; o >= 1; o >>= 1) s += __shfl_xor(s, o, 16);
        if (q == 0) out[(size_t)(blockIdx.x * 8 + nib) * NCLS + c] = ex / s;
    }
}

// ---------------- launch ----------------

extern "C" void kernel_launch(void* const* d_in, const int* in_sizes, int n_in,
                              void* d_out, int out_size, void* d_ws, size_t ws_size,
                              hipStream_t stream) {
    const float* x    = (const float*)d_in[0];
    const int*   ei   = (const int*)d_in[1];
    const float* ew   = (const float*)d_in[2];
    const float* W1   = (const float*)d_in[3];
    const float* b1   = (const float*)d_in[4];
    const float* W2   = (const float*)d_in[5];
    const float* b2   = (const float*)d_in[6];
    const float* Wout = (const float*)d_in[7];
    const float* bout = (const float*)d_in[8];
    const int* row = ei;
    const int* col = ei + NE;

    // workspace; tmp aliases the A/B feature region (consumed by bucket2 before
    // mm64 writes A — launch order guarantees this)
    int*   ip     = (int*)d_ws;
    int*   begA   = ip;                               // 50048
    int*   endA   = ip + 50048;                       // 50048
    float* dinv   = (float*)(ip + 100096);            // 50048
    int*   bkcur  = ip + 150144;                      // 512
    int2*  sedge  = (int2*)(ip + 150656);             // NBK*CAP int2 (~8 MB)
    u16*   A      = (u16*)(ip + 150656 + 2 * NBK * CAP);  // NN*64 bf16 (6.4 MB)
    u16*   B      = A + 3200000;                      // NN*64 bf16 (6.4 MB)
    int2*  tmp    = (int2*)A;                         // NBK*CAP int2 aliased over A+B

    // sort pipeline
    k_init_cur<<<2, 256, 0, stream>>>(bkcur);
    k_bucket1<<<B1B, 512, 0, stream>>>(row, col, ew, bkcur, tmp);
    k_bucket2<<<NBK, 256, 0, stream>>>(bkcur, tmp, sedge, begA, endA, dinv);

    // layer 1
    k_mm64<false><<<NN / 16, 256, 0, stream>>>(x, W1, A);
    k_agg<false><<<NN / 8, 256, 0, stream>>>(A, begA, endA, sedge, dinv, b1, B,
                                             nullptr, nullptr, nullptr);
    // layer 2 + fused head
    k_mm64<true><<<NN / 16, 256, 0, stream>>>(B, W2, A);
    k_agg<true><<<NN / 8, 256, 0, stream>>>(A, begA, endA, sedge, dinv, b2, B,
                                            Wout, bout, (float*)d_out);
}